// Round 2
// baseline (388.538 us; speedup 1.0000x reference)
//
#include <hip/hip_runtime.h>
#include <hip/hip_bf16.h>
#include <stdint.h>

#define N_ATOMS 16384
#define FDIM    128
#define NF      (N_ATOMS * FDIM)   // 2,097,152

__device__ __forceinline__ float silu(float x) {
    return x / (1.0f + expf(-x));
}

// ---------------------------------------------------------------------------
// Kernel 1: phi2 = (silu(embed[atoms] @ w_s1 + b_s1) @ w_s2 + b_s2)[:, 128:384]
// One block = 16 atoms. 256 threads. Output: phi2 as [N][256] fp32.
// ---------------------------------------------------------------------------
__global__ __launch_bounds__(256) void phi_kernel(
    const int* __restrict__ atoms,
    const float* __restrict__ embed,
    const float* __restrict__ w1, const float* __restrict__ b1,
    const float* __restrict__ w2, const float* __restrict__ b2,
    float* __restrict__ phi2)
{
    __shared__ float s0[16][128];
    __shared__ float h[16][128];
    __shared__ int aid[16];
    const int t = threadIdx.x;
    const int row0 = blockIdx.x * 16;
    if (t < 16) aid[t] = atoms[row0 + t];
    __syncthreads();
    for (int idx = t; idx < 16 * 128; idx += 256) {
        int a = idx >> 7, f = idx & 127;
        s0[a][f] = embed[(size_t)aid[a] * 128 + f];
    }
    __syncthreads();

    const int f  = t & 127;
    const int ab = (t >> 7) * 8;   // 0 or 8

    // h = silu(s0 @ w1 + b1)
    float acc[8] = {0, 0, 0, 0, 0, 0, 0, 0};
    for (int k = 0; k < 128; ++k) {
        float w = w1[k * 128 + f];
        #pragma unroll
        for (int a = 0; a < 8; ++a) acc[a] += s0[ab + a][k] * w;
    }
    float bb = b1[f];
    #pragma unroll
    for (int a = 0; a < 8; ++a) h[ab + a][f] = silu(acc[a] + bb);
    __syncthreads();

    // phi parts 2 and 3 only (cols 128..383 of w2 which is 128x384)
    float acc2[8], acc3[8];
    #pragma unroll
    for (int a = 0; a < 8; ++a) { acc2[a] = 0.f; acc3[a] = 0.f; }
    for (int k = 0; k < 128; ++k) {
        float wA = w2[k * 384 + 128 + f];
        float wB = w2[k * 384 + 256 + f];
        #pragma unroll
        for (int a = 0; a < 8; ++a) {
            float hh = h[ab + a][k];
            acc2[a] += hh * wA;
            acc3[a] += hh * wB;
        }
    }
    float bbA = b2[128 + f];
    float bbB = b2[256 + f];
    #pragma unroll
    for (int a = 0; a < 8; ++a) {
        float* dst = phi2 + (size_t)(row0 + ab + a) * 256;
        dst[f]       = acc2[a] + bbA;
        dst[128 + f] = acc3[a] + bbB;
    }
}

// ---------------------------------------------------------------------------
// Kernel 2: per-atom-j aggregation over its 16 in-molecule neighbors.
//   s1[j]    = phi2[j, 0:128]   * sum_i Wg2[e]           -> X[j, 128:256]
//   v1[k][j] = phi2[j, 128:256] * sum_i Wg3[e]*unit[e,k] -> v1 [3][N][128]
// lin_r col c (c in [128,384)) = b_r[c] + sum_r rbf[r]*w_r[r,c]
// One block = one atom j. 256 threads (thread t owns column 128+t).
// ---------------------------------------------------------------------------
__global__ __launch_bounds__(256) void edge_kernel(
    const float* __restrict__ pos,
    const float* __restrict__ w_r, const float* __restrict__ b_r,
    const float* __restrict__ phi2,
    float* __restrict__ X,      // [N][256], we write cols 128..255
    float* __restrict__ v1)     // [3][N][128]
{
    const int j = blockIdx.x;
    const int t = threadIdx.x;
    const int mol0 = (j >> 4) << 4;

    __shared__ float rbf[16][20];
    __shared__ float unitv[16][3];

    const float pjx = pos[j * 3 + 0];
    const float pjy = pos[j * 3 + 1];
    const float pjz = pos[j * 3 + 2];
    const float PI5 = 0.6283185307179586f;  // pi/5

    for (int idx = t; idx < 16 * 20; idx += 256) {
        int nb = idx / 20, r = idx - nb * 20;
        int i = mol0 + nb;
        float dx = pos[i * 3 + 0] - pjx;
        float dy = pos[i * 3 + 1] - pjy;
        float dz = pos[i * 3 + 2] - pjz;
        float d = sqrtf(dx * dx + dy * dy + dz * dz);
        rbf[nb][r] = sinf((float)(r + 1) * PI5 * d) / (d + 1e-8f);
    }
    if (t < 48) {
        int nb = t / 3, k = t - nb * 3;
        int i = mol0 + nb;
        float dx = pos[i * 3 + 0] - pjx;
        float dy = pos[i * 3 + 1] - pjy;
        float dz = pos[i * 3 + 2] - pjz;
        float d = sqrtf(dx * dx + dy * dy + dz * dz);
        float comp = (k == 0) ? dx : ((k == 1) ? dy : dz);
        unitv[nb][k] = comp / (d + 1e-8f);
    }
    __syncthreads();

    const int c = 128 + t;
    float wr[20];
    #pragma unroll
    for (int r = 0; r < 20; ++r) wr[r] = w_r[r * 384 + c];
    const float br = b_r[c];

    float sum2 = 0.f, s3x = 0.f, s3y = 0.f, s3z = 0.f;
    for (int nb = 0; nb < 16; ++nb) {
        float lin = br;
        #pragma unroll
        for (int r = 0; r < 20; ++r) lin += rbf[nb][r] * wr[r];
        float Wg = (lin < 5.0f) ? (0.5f * (cosf(PI5 * lin) + 1.0f)) : 0.0f;
        if (t < 128) {
            sum2 += Wg;
        } else {
            s3x += Wg * unitv[nb][0];
            s3y += Wg * unitv[nb][1];
            s3z += Wg * unitv[nb][2];
        }
    }
    if (t < 128) {
        X[(size_t)j * 256 + 128 + t] = phi2[(size_t)j * 256 + t] * sum2;
    } else {
        int f = t - 128;
        float p3 = phi2[(size_t)j * 256 + 128 + f];
        v1[0 * (size_t)NF + (size_t)j * 128 + f] = p3 * s3x;
        v1[1 * (size_t)NF + (size_t)j * 128 + f] = p3 * s3y;
        v1[2 * (size_t)NF + (size_t)j * 128 + f] = p3 * s3z;
    }
}

// ---------------------------------------------------------------------------
// Generic tiled GEMM: out[M x NC](fp32) = A[M x K](fp32) @ B[K x NC](fp32) + bias
// Block computes 64 rows x 128 cols (col offset c0). 256 threads, 8x4 per thread.
// ---------------------------------------------------------------------------
template <bool SILU>
__device__ __forceinline__ void gemm_tile(
    const float* __restrict__ A, int lda, int K,
    const float* __restrict__ B, int ldb,
    const float* __restrict__ bias,
    float* __restrict__ out, int ldo,
    int row0, int c0)
{
    __shared__ float As[64][130];  // +2 pad: conflict-free 8-row column reads
    const int t = threadIdx.x;
    const int tc = t & 31;   // col group (4 cols each)
    const int tr = t >> 5;   // row group (8 rows each)

    float acc[8][4];
    #pragma unroll
    for (int i = 0; i < 8; ++i)
        #pragma unroll
        for (int ccc = 0; ccc < 4; ++ccc) acc[i][ccc] = 0.f;

    for (int kc = 0; kc < K; kc += 128) {
        __syncthreads();
        for (int idx = t; idx < 64 * 32; idx += 256) {
            int rr = idx >> 5, cc4 = (idx & 31) << 2;
            const float4 v = *(const float4*)(A + (size_t)(row0 + rr) * lda + kc + cc4);
            As[rr][cc4 + 0] = v.x; As[rr][cc4 + 1] = v.y;
            As[rr][cc4 + 2] = v.z; As[rr][cc4 + 3] = v.w;
        }
        __syncthreads();
        for (int k = 0; k < 128; ++k) {
            const float4 bv = *(const float4*)(B + (size_t)(kc + k) * ldb + c0 + tc * 4);
            #pragma unroll
            for (int i = 0; i < 8; ++i) {
                float a = As[tr * 8 + i][k];
                acc[i][0] += a * bv.x;
                acc[i][1] += a * bv.y;
                acc[i][2] += a * bv.z;
                acc[i][3] += a * bv.w;
            }
        }
    }

    float bb[4];
    #pragma unroll
    for (int ccc = 0; ccc < 4; ++ccc) bb[ccc] = bias[c0 + tc * 4 + ccc];
    #pragma unroll
    for (int i = 0; i < 8; ++i) {
        float* dst = out + (size_t)(row0 + tr * 8 + i) * ldo + c0 + tc * 4;
        #pragma unroll
        for (int ccc = 0; ccc < 4; ++ccc) {
            float v = acc[i][ccc] + bb[ccc];
            if (SILU) v = silu(v);
            dst[ccc] = v;
        }
    }
}

// Kernel 3: the six per-axis F x F maps. grid.y in [0,6): y%3 = axis k, y/3 = U/V.
__global__ __launch_bounds__(256) void gemm_uv_kernel(
    const float* __restrict__ v1,
    const float* __restrict__ Uw, const float* __restrict__ Ub,
    const float* __restrict__ Vw, const float* __restrict__ Vb,
    float* __restrict__ Uv, float* __restrict__ Vv)
{
    const int y = blockIdx.y;
    const int k = y % 3;
    const bool isV = (y >= 3);
    const float* A = v1 + (size_t)k * NF;
    const float* B = (isV ? Vw : Uw) + (size_t)k * 128 * 128;
    const float* bias = (isV ? Vb : Ub) + k * 128;
    float* out = (isV ? Vv : Uv) + (size_t)k * NF;
    gemm_tile<false>(A, 128, 128, B, 128, bias, out, 128, blockIdx.x * 64, 0);
}

// Kernels 5/6: generic GEMMs (X@w_u1 -> silu -> H;  H@w_u2 -> m)
template <bool SILU>
__global__ __launch_bounds__(256) void gemm_kernel(
    const float* __restrict__ A, int K,
    const float* __restrict__ B, int ldb,
    const float* __restrict__ bias,
    float* __restrict__ out)
{
    gemm_tile<SILU>(A, K, K, B, ldb, bias, out, ldb, blockIdx.x * 64, blockIdx.y * 128);
}

// Kernel 4: Vn = ||Vv||_k  -> X[:, 0:128]
__global__ __launch_bounds__(256) void vn_kernel(
    const float* __restrict__ Vv, float* __restrict__ X)
{
    const int idx = blockIdx.x * 256 + threadIdx.x;  // j*128+f
    const int j = idx >> 7, f = idx & 127;
    float a = Vv[idx];
    float b = Vv[(size_t)NF + idx];
    float c = Vv[2 * (size_t)NF + idx];
    X[(size_t)j * 256 + f] = sqrtf(a * a + b * b + c * c);
}

// Kernel 7: outputs (float32).
//   delta_s[j,f]   = (sum_k Uv*Vv) * a_sv + a_ss   (out[0 .. NF))
//   delta_v[j,f,k] = a_vv * Uv[k][j][f]            (out[NF + idx*3 + k])
__global__ __launch_bounds__(256) void out_kernel(
    const float* __restrict__ m,
    const float* __restrict__ Uv, const float* __restrict__ Vv,
    float* __restrict__ out)
{
    const int idx = blockIdx.x * 256 + threadIdx.x;  // j*128+f
    const int j = idx >> 7;
    float a_vv = m[(size_t)j * 384 + (idx & 127)];
    float a_sv = m[(size_t)j * 384 + 128 + (idx & 127)];
    float a_ss = m[(size_t)j * 384 + 256 + (idx & 127)];
    float u0 = Uv[idx], u1 = Uv[(size_t)NF + idx], u2 = Uv[2 * (size_t)NF + idx];
    float v0 = Vv[idx], v1 = Vv[(size_t)NF + idx], v2 = Vv[2 * (size_t)NF + idx];
    out[idx] = (u0 * v0 + u1 * v1 + u2 * v2) * a_sv + a_ss;
    float* dv = out + (size_t)NF;
    size_t o = (size_t)idx * 3;
    dv[o + 0] = a_vv * u0;
    dv[o + 1] = a_vv * u1;
    dv[o + 2] = a_vv * u2;
}

// ---------------------------------------------------------------------------
extern "C" void kernel_launch(void* const* d_in, const int* in_sizes, int n_in,
                              void* d_out, int out_size, void* d_ws, size_t ws_size,
                              hipStream_t stream)
{
    const int*   atoms = (const int*)d_in[0];
    const float* pos   = (const float*)d_in[1];
    // d_in[2]=idx_i, d_in[3]=idx_j: analytic pattern (i=e/16, j=(e/256)*16+e%16) — unused
    const float* embed = (const float*)d_in[4];
    const float* w_s1  = (const float*)d_in[5];
    const float* b_s1  = (const float*)d_in[6];
    const float* w_s2  = (const float*)d_in[7];
    const float* b_s2  = (const float*)d_in[8];
    const float* w_r   = (const float*)d_in[9];
    const float* b_r   = (const float*)d_in[10];
    const float* w_u1  = (const float*)d_in[11];
    const float* b_u1  = (const float*)d_in[12];
    const float* w_u2  = (const float*)d_in[13];
    const float* b_u2  = (const float*)d_in[14];
    const float* Uw    = (const float*)d_in[15];
    const float* Ub    = (const float*)d_in[16];
    const float* Vw    = (const float*)d_in[17];
    const float* Vb    = (const float*)d_in[18];

    float* ws   = (float*)d_ws;
    float* buf0 = ws;                                  // phi2 [N][256], later H [N][128]
    float* X    = buf0 + (size_t)N_ATOMS * 256;        // [N][256] = [Vn | s1]
    float* v1   = X    + (size_t)N_ATOMS * 256;        // [3][N][128], later m [N][384]
    float* Uv   = v1   + 3ull * NF;                    // [3][N][128]
    float* Vv   = Uv   + 3ull * NF;                    // [3][N][128]
    // total: N*1664 floats = 109 MB

    float* H = buf0;   // reuse phi2 region after edge_kernel consumed it
    float* m = v1;     // reuse v1 region after gemm_uv consumed it

    phi_kernel<<<N_ATOMS / 16, 256, 0, stream>>>(atoms, embed, w_s1, b_s1, w_s2, b_s2, buf0);
    edge_kernel<<<N_ATOMS, 256, 0, stream>>>(pos, w_r, b_r, buf0, X, v1);
    gemm_uv_kernel<<<dim3(N_ATOMS / 64, 6), 256, 0, stream>>>(v1, Uw, Ub, Vw, Vb, Uv, Vv);
    vn_kernel<<<NF / 256, 256, 0, stream>>>(Vv, X);
    gemm_kernel<true><<<dim3(N_ATOMS / 64, 1), 256, 0, stream>>>(X, 256, w_u1, 128, b_u1, H);
    gemm_kernel<false><<<dim3(N_ATOMS / 64, 3), 256, 0, stream>>>(H, 128, w_u2, 384, b_u2, m);
    out_kernel<<<NF / 256, 256, 0, stream>>>(m, Uv, Vv, (float*)d_out);
}

// Round 3
// 349.519 us; speedup vs baseline: 1.1116x; 1.1116x over previous
//
#include <hip/hip_runtime.h>
#include <hip/hip_bf16.h>
#include <stdint.h>

#define N_ATOMS 16384
#define FDIM    128
#define NF      (N_ATOMS * FDIM)   // 2,097,152

__device__ __forceinline__ float silu(float x) {
    return x / (1.0f + expf(-x));
}

// cos(pi*lin/5) gate using HW cos (input in revolutions, fract-reduced).
__device__ __forceinline__ float gate(float lin) {
    float x = lin * 0.1f;
    x = x - floorf(x);
    float cg = 0.5f * (__builtin_amdgcn_cosf(x) + 1.0f);
    return (lin < 5.0f) ? cg : 0.0f;
}

// ---------------------------------------------------------------------------
// Kernel 1: phi2 = (silu(embed[atoms] @ w_s1 + b_s1) @ w_s2 + b_s2)[:, 128:384]
// One block = 16 atoms. 256 threads. Output: phi2 as [N][256] fp32.
// ---------------------------------------------------------------------------
__global__ __launch_bounds__(256) void phi_kernel(
    const int* __restrict__ atoms,
    const float* __restrict__ embed,
    const float* __restrict__ w1, const float* __restrict__ b1,
    const float* __restrict__ w2, const float* __restrict__ b2,
    float* __restrict__ phi2)
{
    __shared__ float s0[16][128];
    __shared__ float h[16][128];
    __shared__ int aid[16];
    const int t = threadIdx.x;
    const int row0 = blockIdx.x * 16;
    if (t < 16) aid[t] = atoms[row0 + t];
    __syncthreads();
    for (int idx = t; idx < 16 * 128; idx += 256) {
        int a = idx >> 7, f = idx & 127;
        s0[a][f] = embed[(size_t)aid[a] * 128 + f];
    }
    __syncthreads();

    const int f  = t & 127;
    const int ab = (t >> 7) * 8;   // 0 or 8

    float acc[8] = {0, 0, 0, 0, 0, 0, 0, 0};
    for (int k = 0; k < 128; ++k) {
        float w = w1[k * 128 + f];
        #pragma unroll
        for (int a = 0; a < 8; ++a) acc[a] += s0[ab + a][k] * w;
    }
    float bb = b1[f];
    #pragma unroll
    for (int a = 0; a < 8; ++a) h[ab + a][f] = silu(acc[a] + bb);
    __syncthreads();

    float acc2[8], acc3[8];
    #pragma unroll
    for (int a = 0; a < 8; ++a) { acc2[a] = 0.f; acc3[a] = 0.f; }
    for (int k = 0; k < 128; ++k) {
        float wA = w2[k * 384 + 128 + f];
        float wB = w2[k * 384 + 256 + f];
        #pragma unroll
        for (int a = 0; a < 8; ++a) {
            float hh = h[ab + a][k];
            acc2[a] += hh * wA;
            acc3[a] += hh * wB;
        }
    }
    float bbA = b2[128 + f];
    float bbB = b2[256 + f];
    #pragma unroll
    for (int a = 0; a < 8; ++a) {
        float* dst = phi2 + (size_t)(row0 + ab + a) * 256;
        dst[f]       = acc2[a] + bbA;
        dst[128 + f] = acc3[a] + bbB;
    }
}

// ---------------------------------------------------------------------------
// Per-molecule pair setup: positions, pair decode, distances, units, rbf.
// 120 unique pairs (a<b); diagonal handled analytically (rbf=0, unit=0).
// ---------------------------------------------------------------------------
template <bool NEED_UNIT>
__device__ __forceinline__ void setup_mol(
    const float* __restrict__ pos, int mol0, int t,
    float (&rbf)[120][20], float (&unitv)[120][4],
    int (&pa)[120], int (&pb)[120], float (&posS)[16][3])
{
    if (t < 16) {
        posS[t][0] = pos[(mol0 + t) * 3 + 0];
        posS[t][1] = pos[(mol0 + t) * 3 + 1];
        posS[t][2] = pos[(mol0 + t) * 3 + 2];
    }
    if (t < 120) {
        int p = t;
        int b = (int)(0.5f * (1.0f + sqrtf(8.0f * (float)p + 1.0f)));
        while (b * (b - 1) / 2 > p) --b;
        while ((b + 1) * b / 2 <= p) ++b;
        pa[p] = p - b * (b - 1) / 2;
        pb[p] = b;
    }
    __syncthreads();
    if (t < 120) {
        int a = pa[t], b = pb[t];
        float dx = posS[a][0] - posS[b][0];
        float dy = posS[a][1] - posS[b][1];
        float dz = posS[a][2] - posS[b][2];
        float d = sqrtf(dx * dx + dy * dy + dz * dz);
        float inv = 1.0f / (d + 1e-8f);
        if (NEED_UNIT) {
            unitv[t][0] = dx * inv;  // rvec for edge (i=a, j=b)
            unitv[t][1] = dy * inv;
            unitv[t][2] = dz * inv;
            unitv[t][3] = 0.f;
        }
        #pragma unroll
        for (int r = 0; r < 20; ++r) {
            float xr = (float)(r + 1) * d * 0.1f;   // revolutions: sin(2*pi*x) = sin((r+1)*pi*d/5)
            xr = xr - floorf(xr);
            rbf[t][r] = __builtin_amdgcn_sinf(xr) * inv;
        }
    }
    __syncthreads();
}

__device__ __forceinline__ float pair_lin(const float (&rbf)[120][20],
                                          const float (&wr)[20], int p, float br)
{
    const float4* rb = (const float4*)&rbf[p][0];  // row stride 80 B, 16B-aligned
    float lin = br;
    #pragma unroll
    for (int q = 0; q < 5; ++q) {
        float4 rv = rb[q];
        lin += rv.x * wr[4 * q] + rv.y * wr[4 * q + 1]
             + rv.z * wr[4 * q + 2] + rv.w * wr[4 * q + 3];
    }
    return lin;
}

// ---------------------------------------------------------------------------
// Kernel 2a: s1[j][f] = phi2_2[j][f] * sum_i Wg2(d_ij, c=128+f)
// One block = one molecule, 128 threads (thread t owns column c=128+t).
// ---------------------------------------------------------------------------
__global__ __launch_bounds__(128) void edge_s2_kernel(
    const float* __restrict__ pos,
    const float* __restrict__ w_r, const float* __restrict__ b_r,
    const float* __restrict__ phi2,
    float* __restrict__ X)      // [N][256], write cols 128..255
{
    __shared__ float rbf[120][20];
    __shared__ float unitv[120][4];
    __shared__ int pa[120], pb[120];
    __shared__ float posS[16][3];
    const int t = threadIdx.x;
    const int mol0 = blockIdx.x * 16;
    setup_mol<false>(pos, mol0, t, rbf, unitv, pa, pb, posS);

    const int c = 128 + t;
    float wr[20];
    #pragma unroll
    for (int r = 0; r < 20; ++r) wr[r] = w_r[r * 384 + c];
    const float br = b_r[c];

    float acc[16];
    const float wg0 = gate(br);   // diagonal (d=0) contribution, once per atom
    #pragma unroll
    for (int a = 0; a < 16; ++a) acc[a] = wg0;

    #pragma unroll
    for (int b = 1; b < 16; ++b) {
        #pragma unroll
        for (int a = 0; a < b; ++a) {
            const int p = b * (b - 1) / 2 + a;
            float Wg = gate(pair_lin(rbf, wr, p, br));
            acc[a] += Wg;
            acc[b] += Wg;
        }
    }

    #pragma unroll
    for (int a = 0; a < 16; ++a) {
        X[(size_t)(mol0 + a) * 256 + 128 + t] =
            phi2[(size_t)(mol0 + a) * 256 + t] * acc[a];
    }
}

// ---------------------------------------------------------------------------
// Kernel 2b: v1[k][j][f] = phi2_3[j][f] * sum_i Wg3(d_ij, c=256+f) * unit_k(i->j)
// One block = one molecule, 128 threads (thread t owns column c=256+t).
// ---------------------------------------------------------------------------
__global__ __launch_bounds__(128) void edge_s3_kernel(
    const float* __restrict__ pos,
    const float* __restrict__ w_r, const float* __restrict__ b_r,
    const float* __restrict__ phi2,
    float* __restrict__ v1)     // [3][N][128]
{
    __shared__ float rbf[120][20];
    __shared__ float unitv[120][4];
    __shared__ int pa[120], pb[120];
    __shared__ float posS[16][3];
    const int t = threadIdx.x;
    const int mol0 = blockIdx.x * 16;
    setup_mol<true>(pos, mol0, t, rbf, unitv, pa, pb, posS);

    const int c = 256 + t;
    float wr[20];
    #pragma unroll
    for (int r = 0; r < 20; ++r) wr[r] = w_r[r * 384 + c];
    const float br = b_r[c];

    float sx[16], sy[16], sz[16];
    #pragma unroll
    for (int a = 0; a < 16; ++a) { sx[a] = 0.f; sy[a] = 0.f; sz[a] = 0.f; }

    #pragma unroll
    for (int b = 1; b < 16; ++b) {
        #pragma unroll
        for (int a = 0; a < b; ++a) {
            const int p = b * (b - 1) / 2 + a;
            float Wg = gate(pair_lin(rbf, wr, p, br));
            float4 u = *(const float4*)&unitv[p][0];   // u = (pos_a - pos_b)/d
            float gx = Wg * u.x, gy = Wg * u.y, gz = Wg * u.z;
            sx[b] += gx; sy[b] += gy; sz[b] += gz;     // edge (i=a, j=b)
            sx[a] -= gx; sy[a] -= gy; sz[a] -= gz;     // edge (i=b, j=a)
        }
    }

    #pragma unroll
    for (int a = 0; a < 16; ++a) {
        float p3 = phi2[(size_t)(mol0 + a) * 256 + 128 + t];
        size_t base = (size_t)(mol0 + a) * 128 + t;
        v1[base]                  = p3 * sx[a];
        v1[(size_t)NF + base]     = p3 * sy[a];
        v1[2 * (size_t)NF + base] = p3 * sz[a];
    }
}

// ---------------------------------------------------------------------------
// Generic tiled GEMM: out[M x NC](fp32) = A[M x K](fp32) @ B[K x NC](fp32) + bias
// Block computes 64 rows x 128 cols (col offset c0). 256 threads, 8x4 per thread.
// ---------------------------------------------------------------------------
template <bool SILU>
__device__ __forceinline__ void gemm_tile(
    const float* __restrict__ A, int lda, int K,
    const float* __restrict__ B, int ldb,
    const float* __restrict__ bias,
    float* __restrict__ out, int ldo,
    int row0, int c0)
{
    __shared__ float As[64][130];  // +2 pad: conflict-free 8-row column reads
    const int t = threadIdx.x;
    const int tc = t & 31;   // col group (4 cols each)
    const int tr = t >> 5;   // row group (8 rows each)

    float acc[8][4];
    #pragma unroll
    for (int i = 0; i < 8; ++i)
        #pragma unroll
        for (int ccc = 0; ccc < 4; ++ccc) acc[i][ccc] = 0.f;

    for (int kc = 0; kc < K; kc += 128) {
        __syncthreads();
        for (int idx = t; idx < 64 * 32; idx += 256) {
            int rr = idx >> 5, cc4 = (idx & 31) << 2;
            const float4 v = *(const float4*)(A + (size_t)(row0 + rr) * lda + kc + cc4);
            As[rr][cc4 + 0] = v.x; As[rr][cc4 + 1] = v.y;
            As[rr][cc4 + 2] = v.z; As[rr][cc4 + 3] = v.w;
        }
        __syncthreads();
        for (int k = 0; k < 128; ++k) {
            const float4 bv = *(const float4*)(B + (size_t)(kc + k) * ldb + c0 + tc * 4);
            #pragma unroll
            for (int i = 0; i < 8; ++i) {
                float a = As[tr * 8 + i][k];
                acc[i][0] += a * bv.x;
                acc[i][1] += a * bv.y;
                acc[i][2] += a * bv.z;
                acc[i][3] += a * bv.w;
            }
        }
    }

    float bb[4];
    #pragma unroll
    for (int ccc = 0; ccc < 4; ++ccc) bb[ccc] = bias[c0 + tc * 4 + ccc];
    #pragma unroll
    for (int i = 0; i < 8; ++i) {
        float* dst = out + (size_t)(row0 + tr * 8 + i) * ldo + c0 + tc * 4;
        #pragma unroll
        for (int ccc = 0; ccc < 4; ++ccc) {
            float v = acc[i][ccc] + bb[ccc];
            if (SILU) v = silu(v);
            dst[ccc] = v;
        }
    }
}

// Kernel 3: the six per-axis F x F maps. grid.y in [0,6): y%3 = axis k, y/3 = U/V.
__global__ __launch_bounds__(256) void gemm_uv_kernel(
    const float* __restrict__ v1,
    const float* __restrict__ Uw, const float* __restrict__ Ub,
    const float* __restrict__ Vw, const float* __restrict__ Vb,
    float* __restrict__ Uv, float* __restrict__ Vv)
{
    const int y = blockIdx.y;
    const int k = y % 3;
    const bool isV = (y >= 3);
    const float* A = v1 + (size_t)k * NF;
    const float* B = (isV ? Vw : Uw) + (size_t)k * 128 * 128;
    const float* bias = (isV ? Vb : Ub) + k * 128;
    float* out = (isV ? Vv : Uv) + (size_t)k * NF;
    gemm_tile<false>(A, 128, 128, B, 128, bias, out, 128, blockIdx.x * 64, 0);
}

// Kernels 5/6: generic GEMMs (X@w_u1 -> silu -> H;  H@w_u2 -> m)
template <bool SILU>
__global__ __launch_bounds__(256) void gemm_kernel(
    const float* __restrict__ A, int K,
    const float* __restrict__ B, int ldb,
    const float* __restrict__ bias,
    float* __restrict__ out)
{
    gemm_tile<SILU>(A, K, K, B, ldb, bias, out, ldb, blockIdx.x * 64, blockIdx.y * 128);
}

// Kernel 4: Vn = ||Vv||_k  -> X[:, 0:128]
__global__ __launch_bounds__(256) void vn_kernel(
    const float* __restrict__ Vv, float* __restrict__ X)
{
    const int idx = blockIdx.x * 256 + threadIdx.x;  // j*128+f
    const int j = idx >> 7, f = idx & 127;
    float a = Vv[idx];
    float b = Vv[(size_t)NF + idx];
    float c = Vv[2 * (size_t)NF + idx];
    X[(size_t)j * 256 + f] = sqrtf(a * a + b * b + c * c);
}

// Kernel 7: outputs (float32).
__global__ __launch_bounds__(256) void out_kernel(
    const float* __restrict__ m,
    const float* __restrict__ Uv, const float* __restrict__ Vv,
    float* __restrict__ out)
{
    const int idx = blockIdx.x * 256 + threadIdx.x;  // j*128+f
    const int j = idx >> 7;
    float a_vv = m[(size_t)j * 384 + (idx & 127)];
    float a_sv = m[(size_t)j * 384 + 128 + (idx & 127)];
    float a_ss = m[(size_t)j * 384 + 256 + (idx & 127)];
    float u0 = Uv[idx], u1 = Uv[(size_t)NF + idx], u2 = Uv[2 * (size_t)NF + idx];
    float v0 = Vv[idx], v1 = Vv[(size_t)NF + idx], v2 = Vv[2 * (size_t)NF + idx];
    out[idx] = (u0 * v0 + u1 * v1 + u2 * v2) * a_sv + a_ss;
    float* dv = out + (size_t)NF;
    size_t o = (size_t)idx * 3;
    dv[o + 0] = a_vv * u0;
    dv[o + 1] = a_vv * u1;
    dv[o + 2] = a_vv * u2;
}

// ---------------------------------------------------------------------------
extern "C" void kernel_launch(void* const* d_in, const int* in_sizes, int n_in,
                              void* d_out, int out_size, void* d_ws, size_t ws_size,
                              hipStream_t stream)
{
    const int*   atoms = (const int*)d_in[0];
    const float* pos   = (const float*)d_in[1];
    // d_in[2]=idx_i, d_in[3]=idx_j: analytic pattern (i=e/16, j=(e/256)*16+e%16) — unused
    const float* embed = (const float*)d_in[4];
    const float* w_s1  = (const float*)d_in[5];
    const float* b_s1  = (const float*)d_in[6];
    const float* w_s2  = (const float*)d_in[7];
    const float* b_s2  = (const float*)d_in[8];
    const float* w_r   = (const float*)d_in[9];
    const float* b_r   = (const float*)d_in[10];
    const float* w_u1  = (const float*)d_in[11];
    const float* b_u1  = (const float*)d_in[12];
    const float* w_u2  = (const float*)d_in[13];
    const float* b_u2  = (const float*)d_in[14];
    const float* Uw    = (const float*)d_in[15];
    const float* Ub    = (const float*)d_in[16];
    const float* Vw    = (const float*)d_in[17];
    const float* Vb    = (const float*)d_in[18];

    float* ws   = (float*)d_ws;
    float* buf0 = ws;                                  // phi2 [N][256], later H [N][128]
    float* X    = buf0 + (size_t)N_ATOMS * 256;        // [N][256] = [Vn | s1]
    float* v1   = X    + (size_t)N_ATOMS * 256;        // [3][N][128], later m [N][384]
    float* Uv   = v1   + 3ull * NF;                    // [3][N][128]
    float* Vv   = Uv   + 3ull * NF;                    // [3][N][128]
    // total: N*1664 floats = 109 MB

    float* H = buf0;   // reuse phi2 region after edge kernels consumed it
    float* m = v1;     // reuse v1 region after gemm_uv consumed it

    phi_kernel<<<N_ATOMS / 16, 256, 0, stream>>>(atoms, embed, w_s1, b_s1, w_s2, b_s2, buf0);
    edge_s2_kernel<<<N_ATOMS / 16, 128, 0, stream>>>(pos, w_r, b_r, buf0, X);
    edge_s3_kernel<<<N_ATOMS / 16, 128, 0, stream>>>(pos, w_r, b_r, buf0, v1);
    gemm_uv_kernel<<<dim3(N_ATOMS / 64, 6), 256, 0, stream>>>(v1, Uw, Ub, Vw, Vb, Uv, Vv);
    vn_kernel<<<NF / 256, 256, 0, stream>>>(Vv, X);
    gemm_kernel<true><<<dim3(N_ATOMS / 64, 1), 256, 0, stream>>>(X, 256, w_u1, 128, b_u1, H);
    gemm_kernel<false><<<dim3(N_ATOMS / 64, 3), 256, 0, stream>>>(H, 128, w_u2, 384, b_u2, m);
    out_kernel<<<NF / 256, 256, 0, stream>>>(m, Uv, Vv, (float*)d_out);
}

// Round 4
// 227.677 us; speedup vs baseline: 1.7065x; 1.5352x over previous
//
#include <hip/hip_runtime.h>
#include <stdint.h>

#define N_ATOMS 16384
#define FDIM    128
#define NF      (N_ATOMS * FDIM)   // 2,097,152
#define PK      136                // LDS bf16 row stride (128 + 8 pad -> 16B aligned, 2-way banks)

typedef __bf16 bf16;
typedef bf16  bf16x8 __attribute__((ext_vector_type(8)));
typedef float f32x4  __attribute__((ext_vector_type(4)));

#define MFMA(a, b, c) __builtin_amdgcn_mfma_f32_16x16x32_bf16((a), (b), (c), 0, 0, 0)

__device__ __forceinline__ float silu(float x) { return x / (1.0f + expf(-x)); }

// fp32 -> bf16 (round to nearest even), stored as uint16
__device__ __forceinline__ uint16_t f2b(float x) {
    union { float f; uint32_t u; } v; v.f = x;
    uint32_t r = (v.u + 0x7FFFu + ((v.u >> 16) & 1u)) >> 16;
    return (uint16_t)r;
}
__device__ __forceinline__ float b2f(uint16_t u) {
    return __uint_as_float(((uint32_t)u) << 16);
}

// cos(pi*lin/5) gate using HW cos (input in revolutions, fract-reduced).
__device__ __forceinline__ float gate(float lin) {
    float x = lin * 0.1f;
    x = x - floorf(x);
    float cg = 0.5f * (__builtin_amdgcn_cosf(x) + 1.0f);
    return (lin < 5.0f) ? cg : 0.0f;
}

// ---------------------------------------------------------------------------
// Stage B[kc..kc+128)[c0..c0+128) (fp32, row stride ldb) into LDS bt[n][k] bf16,
// transposed so B-fragments are contiguous-k ds_read_b128. 256 threads.
// Caller handles barriers.
// ---------------------------------------------------------------------------
__device__ __forceinline__ void stage_bt(uint16_t* bt, const float* __restrict__ B,
                                         int ldb, int c0, int kc, int t)
{
    const int n  = t & 127;
    const int k0 = (t >> 7) * 64;
    #pragma unroll
    for (int g = 0; g < 8; ++g) {
        union { uint16_t u16[8]; uint4 u4; } pk;
        #pragma unroll
        for (int j = 0; j < 8; ++j)
            pk.u16[j] = f2b(B[(size_t)(kc + k0 + 8 * g + j) * ldb + c0 + n]);
        *(uint4*)(bt + (size_t)n * PK + k0 + 8 * g) = pk.u4;
    }
}

// ---------------------------------------------------------------------------
// Kernel 1 (fused MLP, MFMA):
//   phi2 = (silu(embed[atoms] @ w_s1 + b_s1) @ w_s2 + b_s2)[:, 128:384]  (bf16)
// Block = 64 rows, 256 threads (4 waves x 16 rows).
// ---------------------------------------------------------------------------
__global__ __launch_bounds__(256) void phi_kernel(
    const int* __restrict__ atoms,
    const float* __restrict__ embed,
    const float* __restrict__ w1, const float* __restrict__ b1,
    const float* __restrict__ w2, const float* __restrict__ b2,
    uint16_t* __restrict__ phi2)   // [N][256] bf16
{
    __shared__ uint16_t aS[64 * PK];     // s0 (gathered embed), then h
    __shared__ uint16_t bt[128 * PK];
    const int t = threadIdx.x;
    const int w = t >> 6, l = t & 63;
    const int lrow = l & 15, lk = (l >> 4) * 8;
    const int r0 = blockIdx.x * 64;

    // stage s0 = bf16(embed[atoms[r]])
    {
        const int row = t & 63, ch = (t >> 6) * 32;
        const int aid = atoms[r0 + row];
        const float* src = embed + (size_t)aid * 128 + ch;
        #pragma unroll
        for (int g = 0; g < 4; ++g) {
            float4 v0 = ((const float4*)src)[2 * g];
            float4 v1 = ((const float4*)src)[2 * g + 1];
            union { uint16_t u16[8]; uint4 u4; } pk;
            pk.u16[0] = f2b(v0.x); pk.u16[1] = f2b(v0.y);
            pk.u16[2] = f2b(v0.z); pk.u16[3] = f2b(v0.w);
            pk.u16[4] = f2b(v1.x); pk.u16[5] = f2b(v1.y);
            pk.u16[6] = f2b(v1.z); pk.u16[7] = f2b(v1.w);
            *(uint4*)(aS + (size_t)row * PK + ch + 8 * g) = pk.u4;
        }
    }

    // layer 1: acc1 = s0 @ w_s1  (K=128)
    f32x4 acc1[8];
    #pragma unroll
    for (int n = 0; n < 8; ++n) acc1[n] = f32x4{0.f, 0.f, 0.f, 0.f};
    __syncthreads();
    stage_bt(bt, w1, 128, 0, 0, t);
    __syncthreads();
    #pragma unroll
    for (int ks = 0; ks < 128; ks += 32) {
        bf16x8 af = *(const bf16x8*)(aS + (size_t)(16 * w + lrow) * PK + ks + lk);
        #pragma unroll
        for (int n = 0; n < 8; ++n) {
            bf16x8 bfr = *(const bf16x8*)(bt + (size_t)(16 * n + lrow) * PK + ks + lk);
            acc1[n] = MFMA(af, bfr, acc1[n]);
        }
    }
    __syncthreads();   // everyone done reading s0
    // h = silu(acc1 + b1) -> aS (reuse)
    #pragma unroll
    for (int n = 0; n < 8; ++n) {
        int col = 16 * n + lrow;
        float bb = b1[col];
        #pragma unroll
        for (int i = 0; i < 4; ++i) {
            int rl = 16 * w + (l >> 4) * 4 + i;
            aS[(size_t)rl * PK + col] = f2b(silu(acc1[n][i] + bb));
        }
    }

    // layer 2: two col-chunks of w_s2 (cols 128..255, 256..383)
    for (int cc = 0; cc < 2; ++cc) {
        __syncthreads();
        stage_bt(bt, w2, 384, 128 + 128 * cc, 0, t);
        __syncthreads();
        f32x4 acc[8];
        #pragma unroll
        for (int n = 0; n < 8; ++n) acc[n] = f32x4{0.f, 0.f, 0.f, 0.f};
        #pragma unroll
        for (int ks = 0; ks < 128; ks += 32) {
            bf16x8 af = *(const bf16x8*)(aS + (size_t)(16 * w + lrow) * PK + ks + lk);
            #pragma unroll
            for (int n = 0; n < 8; ++n) {
                bf16x8 bfr = *(const bf16x8*)(bt + (size_t)(16 * n + lrow) * PK + ks + lk);
                acc[n] = MFMA(af, bfr, acc[n]);
            }
        }
        #pragma unroll
        for (int n = 0; n < 8; ++n) {
            int col = 16 * n + lrow;
            float bb = b2[128 + 128 * cc + col];
            #pragma unroll
            for (int i = 0; i < 4; ++i) {
                int row = r0 + 16 * w + (l >> 4) * 4 + i;
                phi2[(size_t)row * 256 + 128 * cc + col] = f2b(acc[n][i] + bb);
            }
        }
    }
}

// ---------------------------------------------------------------------------
// Per-molecule pair setup (unchanged from round 3)
// ---------------------------------------------------------------------------
template <bool NEED_UNIT>
__device__ __forceinline__ void setup_mol(
    const float* __restrict__ pos, int mol0, int t,
    float (&rbf)[120][20], float (&unitv)[120][4],
    int (&pa)[120], int (&pb)[120], float (&posS)[16][3])
{
    if (t < 16) {
        posS[t][0] = pos[(mol0 + t) * 3 + 0];
        posS[t][1] = pos[(mol0 + t) * 3 + 1];
        posS[t][2] = pos[(mol0 + t) * 3 + 2];
    }
    if (t < 120) {
        int p = t;
        int b = (int)(0.5f * (1.0f + sqrtf(8.0f * (float)p + 1.0f)));
        while (b * (b - 1) / 2 > p) --b;
        while ((b + 1) * b / 2 <= p) ++b;
        pa[p] = p - b * (b - 1) / 2;
        pb[p] = b;
    }
    __syncthreads();
    if (t < 120) {
        int a = pa[t], b = pb[t];
        float dx = posS[a][0] - posS[b][0];
        float dy = posS[a][1] - posS[b][1];
        float dz = posS[a][2] - posS[b][2];
        float d = sqrtf(dx * dx + dy * dy + dz * dz);
        float inv = 1.0f / (d + 1e-8f);
        if (NEED_UNIT) {
            unitv[t][0] = dx * inv;
            unitv[t][1] = dy * inv;
            unitv[t][2] = dz * inv;
            unitv[t][3] = 0.f;
        }
        #pragma unroll
        for (int r = 0; r < 20; ++r) {
            float xr = (float)(r + 1) * d * 0.1f;
            xr = xr - floorf(xr);
            rbf[t][r] = __builtin_amdgcn_sinf(xr) * inv;
        }
    }
    __syncthreads();
}

__device__ __forceinline__ float pair_lin(const float (&rbf)[120][20],
                                          const float (&wr)[20], int p, float br)
{
    const float4* rb = (const float4*)&rbf[p][0];
    float lin = br;
    #pragma unroll
    for (int q = 0; q < 5; ++q) {
        float4 rv = rb[q];
        lin += rv.x * wr[4 * q] + rv.y * wr[4 * q + 1]
             + rv.z * wr[4 * q + 2] + rv.w * wr[4 * q + 3];
    }
    return lin;
}

// ---------------------------------------------------------------------------
// Kernel 2a: s1 -> X cols 128..255 (bf16)
// ---------------------------------------------------------------------------
__global__ __launch_bounds__(128) void edge_s2_kernel(
    const float* __restrict__ pos,
    const float* __restrict__ w_r, const float* __restrict__ b_r,
    const uint16_t* __restrict__ phi2,
    uint16_t* __restrict__ X)
{
    __shared__ float rbf[120][20];
    __shared__ float unitv[120][4];
    __shared__ int pa[120], pb[120];
    __shared__ float posS[16][3];
    const int t = threadIdx.x;
    const int mol0 = blockIdx.x * 16;
    setup_mol<false>(pos, mol0, t, rbf, unitv, pa, pb, posS);

    const int c = 128 + t;
    float wr[20];
    #pragma unroll
    for (int r = 0; r < 20; ++r) wr[r] = w_r[r * 384 + c];
    const float br = b_r[c];

    float acc[16];
    const float wg0 = gate(br);
    #pragma unroll
    for (int a = 0; a < 16; ++a) acc[a] = wg0;

    #pragma unroll
    for (int b = 1; b < 16; ++b) {
        #pragma unroll
        for (int a = 0; a < b; ++a) {
            const int p = b * (b - 1) / 2 + a;
            float Wg = gate(pair_lin(rbf, wr, p, br));
            acc[a] += Wg;
            acc[b] += Wg;
        }
    }

    #pragma unroll
    for (int a = 0; a < 16; ++a) {
        X[(size_t)(mol0 + a) * 256 + 128 + t] =
            f2b(b2f(phi2[(size_t)(mol0 + a) * 256 + t]) * acc[a]);
    }
}

// ---------------------------------------------------------------------------
// Kernel 2b: v1 (bf16, [3][N][128])
// ---------------------------------------------------------------------------
__global__ __launch_bounds__(128) void edge_s3_kernel(
    const float* __restrict__ pos,
    const float* __restrict__ w_r, const float* __restrict__ b_r,
    const uint16_t* __restrict__ phi2,
    uint16_t* __restrict__ v1)
{
    __shared__ float rbf[120][20];
    __shared__ float unitv[120][4];
    __shared__ int pa[120], pb[120];
    __shared__ float posS[16][3];
    const int t = threadIdx.x;
    const int mol0 = blockIdx.x * 16;
    setup_mol<true>(pos, mol0, t, rbf, unitv, pa, pb, posS);

    const int c = 256 + t;
    float wr[20];
    #pragma unroll
    for (int r = 0; r < 20; ++r) wr[r] = w_r[r * 384 + c];
    const float br = b_r[c];

    float sx[16], sy[16], sz[16];
    #pragma unroll
    for (int a = 0; a < 16; ++a) { sx[a] = 0.f; sy[a] = 0.f; sz[a] = 0.f; }

    #pragma unroll
    for (int b = 1; b < 16; ++b) {
        #pragma unroll
        for (int a = 0; a < b; ++a) {
            const int p = b * (b - 1) / 2 + a;
            float Wg = gate(pair_lin(rbf, wr, p, br));
            float4 u = *(const float4*)&unitv[p][0];
            float gx = Wg * u.x, gy = Wg * u.y, gz = Wg * u.z;
            sx[b] += gx; sy[b] += gy; sz[b] += gz;
            sx[a] -= gx; sy[a] -= gy; sz[a] -= gz;
        }
    }

    #pragma unroll
    for (int a = 0; a < 16; ++a) {
        float p3 = b2f(phi2[(size_t)(mol0 + a) * 256 + 128 + t]);
        size_t base = (size_t)(mol0 + a) * 128 + t;
        v1[base]                  = f2b(p3 * sx[a]);
        v1[(size_t)NF + base]     = f2b(p3 * sy[a]);
        v1[2 * (size_t)NF + base] = f2b(p3 * sz[a]);
    }
}

// ---------------------------------------------------------------------------
// Kernel 3 (MFMA): Uv/Vv = v1[k] @ {Uw,Vw}[k] + bias.  grid (M/64, 6).
// A = v1 bf16, fragments loaded straight from global.
// ---------------------------------------------------------------------------
__global__ __launch_bounds__(256) void uv_kernel(
    const uint16_t* __restrict__ v1,
    const float* __restrict__ Uw, const float* __restrict__ Ub,
    const float* __restrict__ Vw, const float* __restrict__ Vb,
    float* __restrict__ Uv, float* __restrict__ Vv)
{
    __shared__ uint16_t bt[128 * PK];
    const int y = blockIdx.y;
    const int k = y % 3;
    const bool isV = (y >= 3);
    const float* B    = (isV ? Vw : Uw) + (size_t)k * 128 * 128;
    const float* bias = (isV ? Vb : Ub) + k * 128;
    const uint16_t* A = v1 + (size_t)k * NF;
    float* out = (isV ? Vv : Uv) + (size_t)k * NF;

    const int t = threadIdx.x;
    const int w = t >> 6, l = t & 63;
    const int lrow = l & 15, lk = (l >> 4) * 8;
    const int r0 = blockIdx.x * 64;

    stage_bt(bt, B, 128, 0, 0, t);
    __syncthreads();

    f32x4 acc[8];
    #pragma unroll
    for (int n = 0; n < 8; ++n) acc[n] = f32x4{0.f, 0.f, 0.f, 0.f};

    #pragma unroll
    for (int ks = 0; ks < 128; ks += 32) {
        bf16x8 af = *(const bf16x8*)(A + (size_t)(r0 + 16 * w + lrow) * 128 + ks + lk);
        #pragma unroll
        for (int n = 0; n < 8; ++n) {
            bf16x8 bfr = *(const bf16x8*)(bt + (size_t)(16 * n + lrow) * PK + ks + lk);
            acc[n] = MFMA(af, bfr, acc[n]);
        }
    }

    #pragma unroll
    for (int n = 0; n < 8; ++n) {
        int col = 16 * n + lrow;
        float bb = bias[col];
        #pragma unroll
        for (int i = 0; i < 4; ++i) {
            int row = r0 + 16 * w + (l >> 4) * 4 + i;
            out[(size_t)row * 128 + col] = acc[n][i] + bb;
        }
    }
}

// ---------------------------------------------------------------------------
// Kernel 4: Vn = ||Vv||  -> X cols 0..127 (bf16)
// ---------------------------------------------------------------------------
__global__ __launch_bounds__(256) void vn_kernel(
    const float* __restrict__ Vv, uint16_t* __restrict__ X)
{
    const int idx = blockIdx.x * 256 + threadIdx.x;
    const int j = idx >> 7, f = idx & 127;
    float a = Vv[idx];
    float b = Vv[(size_t)NF + idx];
    float c = Vv[2 * (size_t)NF + idx];
    X[(size_t)j * 256 + f] = f2b(sqrtf(a * a + b * b + c * c));
}

// ---------------------------------------------------------------------------
// Kernel 5 (fused update MLP + epilogue, MFMA):
//   m = silu(X @ w_u1 + b_u1) @ w_u2 + b_u2  (held in registers)
//   delta_s = (sum_k Uv*Vv)*a_sv + a_ss ; delta_v = a_vv*Uv
// Block = 64 rows, 256 threads.
// ---------------------------------------------------------------------------
__global__ __launch_bounds__(256) void update_kernel(
    const uint16_t* __restrict__ Xb,   // [N][256] bf16
    const float* __restrict__ w_u1, const float* __restrict__ b_u1,
    const float* __restrict__ w_u2, const float* __restrict__ b_u2,
    const float* __restrict__ Uv, const float* __restrict__ Vv,
    float* __restrict__ out)
{
    __shared__ uint16_t bt[128 * PK];
    __shared__ uint16_t hS[64 * PK];
    const int t = threadIdx.x;
    const int w = t >> 6, l = t & 63;
    const int lrow = l & 15, lk = (l >> 4) * 8;
    const int r0 = blockIdx.x * 64;

    // layer 1: acc1 = X @ w_u1  (K=256, two staged chunks)
    f32x4 acc1[8];
    #pragma unroll
    for (int n = 0; n < 8; ++n) acc1[n] = f32x4{0.f, 0.f, 0.f, 0.f};
    for (int kc = 0; kc < 256; kc += 128) {
        __syncthreads();
        stage_bt(bt, w_u1, 128, 0, kc, t);
        __syncthreads();
        #pragma unroll
        for (int ks = 0; ks < 128; ks += 32) {
            bf16x8 af = *(const bf16x8*)(Xb + (size_t)(r0 + 16 * w + lrow) * 256 + kc + ks + lk);
            #pragma unroll
            for (int n = 0; n < 8; ++n) {
                bf16x8 bfr = *(const bf16x8*)(bt + (size_t)(16 * n + lrow) * PK + ks + lk);
                acc1[n] = MFMA(af, bfr, acc1[n]);
            }
        }
    }
    // h = silu(acc1 + b_u1) -> hS
    #pragma unroll
    for (int n = 0; n < 8; ++n) {
        int col = 16 * n + lrow;
        float bb = b_u1[col];
        #pragma unroll
        for (int i = 0; i < 4; ++i) {
            int rl = 16 * w + (l >> 4) * 4 + i;
            hS[(size_t)rl * PK + col] = f2b(silu(acc1[n][i] + bb));
        }
    }

    // layer 2: three col-chunks of w_u2, kept in registers
    f32x4 macc[3][8];
    #pragma unroll
    for (int cc = 0; cc < 3; ++cc)
        #pragma unroll
        for (int n = 0; n < 8; ++n) macc[cc][n] = f32x4{0.f, 0.f, 0.f, 0.f};

    for (int cc = 0; cc < 3; ++cc) {
        __syncthreads();
        stage_bt(bt, w_u2, 384, 128 * cc, 0, t);
        __syncthreads();
        #pragma unroll
        for (int ks = 0; ks < 128; ks += 32) {
            bf16x8 af = *(const bf16x8*)(hS + (size_t)(16 * w + lrow) * PK + ks + lk);
            #pragma unroll
            for (int n = 0; n < 8; ++n) {
                bf16x8 bfr = *(const bf16x8*)(bt + (size_t)(16 * n + lrow) * PK + ks + lk);
                macc[cc][n] = MFMA(af, bfr, macc[cc][n]);
            }
        }
    }

    // epilogue
    float* dv = out + (size_t)NF;
    #pragma unroll
    for (int n = 0; n < 8; ++n) {
        int f = 16 * n + lrow;
        float bvv = b_u2[f], bsv = b_u2[128 + f], bss = b_u2[256 + f];
        #pragma unroll
        for (int i = 0; i < 4; ++i) {
            int row = r0 + 16 * w + (l >> 4) * 4 + i;
            float a_vv = macc[0][n][i] + bvv;
            float a_sv = macc[1][n][i] + bsv;
            float a_ss = macc[2][n][i] + bss;
            size_t base = (size_t)row * 128 + f;
            float u0 = Uv[base], u1 = Uv[(size_t)NF + base], u2 = Uv[2 * (size_t)NF + base];
            float v0 = Vv[base], v1 = Vv[(size_t)NF + base], v2 = Vv[2 * (size_t)NF + base];
            out[base] = (u0 * v0 + u1 * v1 + u2 * v2) * a_sv + a_ss;
            size_t o = base * 3;
            dv[o + 0] = a_vv * u0;
            dv[o + 1] = a_vv * u1;
            dv[o + 2] = a_vv * u2;
        }
    }
}

// ---------------------------------------------------------------------------
extern "C" void kernel_launch(void* const* d_in, const int* in_sizes, int n_in,
                              void* d_out, int out_size, void* d_ws, size_t ws_size,
                              hipStream_t stream)
{
    const int*   atoms = (const int*)d_in[0];
    const float* pos   = (const float*)d_in[1];
    // d_in[2]=idx_i, d_in[3]=idx_j: analytic pattern — unused
    const float* embed = (const float*)d_in[4];
    const float* w_s1  = (const float*)d_in[5];
    const float* b_s1  = (const float*)d_in[6];
    const float* w_s2  = (const float*)d_in[7];
    const float* b_s2  = (const float*)d_in[8];
    const float* w_r   = (const float*)d_in[9];
    const float* b_r   = (const float*)d_in[10];
    const float* w_u1  = (const float*)d_in[11];
    const float* b_u1  = (const float*)d_in[12];
    const float* w_u2  = (const float*)d_in[13];
    const float* b_u2  = (const float*)d_in[14];
    const float* Uw    = (const float*)d_in[15];
    const float* Ub    = (const float*)d_in[16];
    const float* Vw    = (const float*)d_in[17];
    const float* Vb    = (const float*)d_in[18];

    uint16_t* phi2 = (uint16_t*)d_ws;                    // [N][256] bf16
    uint16_t* Xb   = phi2 + (size_t)N_ATOMS * 256;       // [N][256] bf16 = [Vn | s1]
    uint16_t* v1b  = Xb   + (size_t)N_ATOMS * 256;       // [3][N][128] bf16
    float*    Uv   = (float*)(v1b + 3ull * NF);          // [3][N][128] fp32
    float*    Vv   = Uv + 3ull * NF;                     // [3][N][128] fp32
    // total ~80 MB

    phi_kernel<<<N_ATOMS / 64, 256, 0, stream>>>(atoms, embed, w_s1, b_s1, w_s2, b_s2, phi2);
    edge_s2_kernel<<<N_ATOMS / 16, 128, 0, stream>>>(pos, w_r, b_r, phi2, Xb);
    edge_s3_kernel<<<N_ATOMS / 16, 128, 0, stream>>>(pos, w_r, b_r, phi2, v1b);
    uv_kernel<<<dim3(N_ATOMS / 64, 6), 256, 0, stream>>>(v1b, Uw, Ub, Vw, Vb, Uv, Vv);
    vn_kernel<<<NF / 256, 256, 0, stream>>>(Vv, Xb);
    update_kernel<<<N_ATOMS / 64, 256, 0, stream>>>(Xb, w_u1, b_u1, w_u2, b_u2, Uv, Vv, (float*)d_out);
}